// Round 4
// baseline (633.682 us; speedup 1.0000x reference)
//
#include <hip/hip_runtime.h>
#include <stdint.h>

#define N_DET 20000
#define N_CLS 80
#define NELEM (N_DET * N_CLS)
#define TOPK  1000
#define CONF  0.05f
#define NMST  0.5f
#define CANDS 1280
#define SORTN 2048

typedef unsigned long long u64;
typedef unsigned int u32;

__device__ inline u64 shfl64(u64 v, int src) {
  int lo = __shfl((int)(u32)v, src, 64);
  int hi = __shfl((int)(v >> 32), src, 64);
  return ((u64)(u32)hi << 32) | (u32)lo;
}

// ---------------------------------------------------------------------------
// Workspace layout (total 1,624,320 B — NO overlaps; ws>=1,640,960 proven R1):
//   T16     @ 0        (320)
//   prefA   @ 320      (320)
//   tgtA    @ 640      (320)
//   cnt     @ 960      (320)
//   top_s   @ 1280     (320000)
//   top_idx @ 321280   (320000)
//   cls_out @ 641280   (40960)
//   ghistA  @ 682240   (40960)   [80][128] u32
//   ghistB  @ 723200   (81920)   [80][256] u32
//   cand    @ 805120   (819200)  [80][1280] u64
// ---------------------------------------------------------------------------
#define OFF_T16    0
#define OFF_PREFA  320
#define OFF_TGTA   640
#define OFF_CNT    960
#define OFF_TOPS   1280
#define OFF_TOPI   321280
#define OFF_CLSOUT 641280
#define OFF_GHA    682240
#define OFF_GHB    723200
#define OFF_CAND   805120

// ---------------------------------------------------------------------------
// Pass A: level-0 histogram, bins = float-bits >> 23 (clamped to 127).
// Coalesced float4 reads of the native [N_DET][N_CLS] layout.
// base = 4*v is a multiple of 4 -> classes c0..c0+3, never wraps (80%4==0).
// ---------------------------------------------------------------------------
__global__ __launch_bounds__(256) void k_histA(
    const float* __restrict__ S, u32* __restrict__ gh) {
  __shared__ u32 h[N_CLS * 129];
  for (int i = threadIdx.x; i < N_CLS * 129; i += 256) h[i] = 0;
  __syncthreads();
  const int per = NELEM / 4 / 160;  // 2500 float4 per block
  const float4* S4 = (const float4*)S;
  const int v0 = blockIdx.x * per;
  for (int v = v0 + threadIdx.x; v < v0 + per; v += 256) {
    float4 f = S4[v];
    int c0 = (v * 4) % N_CLS;
    u32 b0 = __float_as_uint(f.x) >> 23; if (b0 > 127u) b0 = 127u;
    u32 b1 = __float_as_uint(f.y) >> 23; if (b1 > 127u) b1 = 127u;
    u32 b2 = __float_as_uint(f.z) >> 23; if (b2 > 127u) b2 = 127u;
    u32 b3 = __float_as_uint(f.w) >> 23; if (b3 > 127u) b3 = 127u;
    atomicAdd(&h[(c0 + 0) * 129 + b0], 1u);
    atomicAdd(&h[(c0 + 1) * 129 + b1], 1u);
    atomicAdd(&h[(c0 + 2) * 129 + b2], 1u);
    atomicAdd(&h[(c0 + 3) * 129 + b3], 1u);
  }
  __syncthreads();
  for (int i = threadIdx.x; i < N_CLS * 128; i += 256) {
    u32 v = h[(i >> 7) * 129 + (i & 127)];
    if (v) atomicAdd(&gh[i], v);
  }
}

__global__ void k_thrA(const u32* __restrict__ gh, u32* __restrict__ prefA,
                       u32* __restrict__ tgtA) {
  const int c = threadIdx.x;
  if (c >= N_CLS) return;
  u32 acc = 0;
  for (int b = 127; b >= 0; --b) {
    u32 hv = gh[c * 128 + b];
    acc += hv;
    if (acc >= TOPK) { prefA[c] = (u32)b; tgtA[c] = TOPK - (acc - hv); return; }
  }
  prefA[c] = 0; tgtA[c] = TOPK;
}

// ---------------------------------------------------------------------------
// Pass B: level-1 histogram over bits [22:15] for elements in the level-0 bin.
// ---------------------------------------------------------------------------
__global__ __launch_bounds__(256) void k_histB(
    const float* __restrict__ S, const u32* __restrict__ prefA,
    u32* __restrict__ gh) {
  __shared__ u32 h[N_CLS * 257];
  __shared__ u32 pA[N_CLS];
  for (int i = threadIdx.x; i < N_CLS * 257; i += 256) h[i] = 0;
  for (int i = threadIdx.x; i < N_CLS; i += 256) pA[i] = prefA[i];
  __syncthreads();
  const int per = NELEM / 4 / 160;
  const float4* S4 = (const float4*)S;
  const int v0 = blockIdx.x * per;
  for (int v = v0 + threadIdx.x; v < v0 + per; v += 256) {
    float4 f = S4[v];
    int c0 = (v * 4) % N_CLS;
    u32 bb[4] = {__float_as_uint(f.x), __float_as_uint(f.y),
                 __float_as_uint(f.z), __float_as_uint(f.w)};
    #pragma unroll
    for (int k = 0; k < 4; ++k) {
      u32 e = bb[k] >> 23; if (e > 127u) e = 127u;
      if (e == pA[c0 + k])
        atomicAdd(&h[(c0 + k) * 257 + ((bb[k] >> 15) & 0xFF)], 1u);
    }
  }
  __syncthreads();
  for (int i = threadIdx.x; i < N_CLS * 256; i += 256) {
    u32 v = h[(i >> 8) * 257 + (i & 255)];
    if (v) atomicAdd(&gh[i], v);
  }
}

__global__ void k_thrB(const u32* __restrict__ gh, const u32* __restrict__ prefA,
                       const u32* __restrict__ tgtA, u32* __restrict__ T16) {
  const int c = threadIdx.x;
  if (c >= N_CLS) return;
  const u32 tgt = tgtA[c];
  u32 acc = 0, B1 = 0;
  for (int b = 255; b >= 0; --b) {
    acc += gh[c * 256 + b];
    if (acc >= tgt) { B1 = (u32)b; break; }
  }
  T16[c] = (prefA[c] << 23) | (B1 << 15);
}

// ---------------------------------------------------------------------------
// Scatter: collect (bits, ~row) for bits >= T16[class] into per-class lists.
// ~1000 + (threshold-bin tail ~40) entries per class; CANDS=1280 has margin.
// ---------------------------------------------------------------------------
__global__ __launch_bounds__(256) void k_scatter(
    const float* __restrict__ S, const u32* __restrict__ T16,
    u32* __restrict__ cnt, u64* __restrict__ cand) {
  __shared__ u32 tl[N_CLS];
  for (int i = threadIdx.x; i < N_CLS; i += 256) tl[i] = T16[i];
  __syncthreads();
  const int per = NELEM / 4 / 160;
  const float4* S4 = (const float4*)S;
  const int v0 = blockIdx.x * per;
  for (int v = v0 + threadIdx.x; v < v0 + per; v += 256) {
    float4 f = S4[v];
    const int base = v * 4;
    const int c0 = base % N_CLS;
    const u32 row = (u32)(base / N_CLS);
    u32 bb[4] = {__float_as_uint(f.x), __float_as_uint(f.y),
                 __float_as_uint(f.z), __float_as_uint(f.w)};
    #pragma unroll
    for (int k = 0; k < 4; ++k) {
      if (bb[k] >= tl[c0 + k]) {
        u32 p = atomicAdd(&cnt[c0 + k], 1u);
        if (p < CANDS)
          cand[(size_t)(c0 + k) * CANDS + p] = ((u64)bb[k] << 32) | (u32)(~row);
      }
    }
  }
}

// ---------------------------------------------------------------------------
// Per-class bitonic sort of candidates -> top-1000 scores + box indices.
// Key (bits<<32)|~row gives score-desc, index-asc (jax top_k tie-break).
// ---------------------------------------------------------------------------
__global__ __launch_bounds__(256) void k_sort(
    const u64* __restrict__ cand, const u32* __restrict__ cnt,
    float* __restrict__ top_s, u32* __restrict__ top_idx) {
  const int c = blockIdx.x, t = threadIdx.x;
  __shared__ u64 keys[SORTN];
  u32 n = cnt[c]; if (n > CANDS) n = CANDS;
  for (int i = t; i < SORTN; i += 256)
    keys[i] = (i < (int)n) ? cand[(size_t)c * CANDS + i] : 0ull;
  __syncthreads();
  for (int k = 2; k <= SORTN; k <<= 1)
    for (int j = k >> 1; j > 0; j >>= 1) {
      for (int p = t; p < SORTN / 2; p += 256) {
        int i  = ((p & ~(j - 1)) << 1) | (p & (j - 1));
        int ix = i | j;
        bool up = (i & k) == 0;
        u64 a = keys[i], b = keys[ix];
        if (up ? (a < b) : (a > b)) { keys[i] = b; keys[ix] = a; }
      }
      __syncthreads();
    }
  for (int i = t; i < TOPK; i += 256) {
    u64 kk = keys[i];
    u32 idx = ~(u32)kk;
    if (kk == 0ull || idx >= N_DET) idx = 0;  // pathological pad only
    top_s[c * TOPK + i] = __uint_as_float((u32)(kk >> 32));
    top_idx[c * TOPK + i] = idx;
  }
}

// ---------------------------------------------------------------------------
// NMS: mask phase (16 waves, all pairs -> 1000x1000 bitmask in LDS), then
// serial greedy sweep on wave 0 using v_readlane (~20 cy/step dependency
// chain instead of ds_bpermute's ~130), then compact top-100 kept scores.
// ---------------------------------------------------------------------------
__global__ __launch_bounds__(1024) void k_nms(
    const float* __restrict__ top_s, const u32* __restrict__ top_idx,
    const float* __restrict__ boxes, float* __restrict__ cls_out) {
  const int c = blockIdx.x;
  const int tid = threadIdx.x, wave = tid >> 6, lane = tid & 63;
  __shared__ float4 sbox[TOPK];     // 16000 B
  __shared__ float sarea[TOPK];     //  4000 B
  __shared__ u64 maskL[TOPK * 16];  // 128000 B

  // stage: gather top-1000 boxes via indices (idx already bounds-checked)
  for (int i = tid; i < TOPK; i += 1024) {
    u32 idx = top_idx[c * TOPK + i];
    if (idx >= N_DET) idx = 0;
    float4 b = ((const float4*)boxes)[idx];
    sbox[i] = b;
    sarea[i] = (b.z - b.x) * (b.w - b.y);
  }
  __syncthreads();

  // column boxes in registers (static-indexed)
  float4 cb[16]; float ca[16];
  #pragma unroll
  for (int s = 0; s < 16; ++s) {
    int j = s * 64 + lane;
    cb[s] = (j < TOPK) ? sbox[j] : make_float4(0.f, 0.f, 0.f, 0.f);
    ca[s] = (j < TOPK) ? sarea[j] : 0.f;
  }

  // mask phase: rows striped over 16 waves
  for (int i = wave; i < TOPK; i += 16) {
    float4 bi = sbox[i];
    float ai = sarea[i];
    const int s0 = i >> 6;
    u64 w = 0;
    #pragma unroll
    for (int s = 0; s < 16; ++s) {
      if (s >= s0) {
        int j = s * 64 + lane;
        bool sup = false;
        if (j < TOPK && j > i) {
          #pragma clang fp contract(off)
          float iw = fmaxf(fminf(bi.z, cb[s].z) - fmaxf(bi.x, cb[s].x), 0.0f);
          float ih = fmaxf(fminf(bi.w, cb[s].w) - fmaxf(bi.y, cb[s].y), 0.0f);
          float inter = iw * ih;
          float iou = inter / (ai + ca[s] - inter + 1e-9f);
          sup = iou > NMST;
        }
        u64 bal = __ballot(sup);
        if (lane == s) w = bal;
      }
    }
    if (lane < 16) maskL[i * 16 + lane] = w;
  }
  __syncthreads();

  // sweep phase: wave 0 only
  if (wave == 0) {
    u64 kw = 0;
    for (int s = 0; s < 16; ++s) {
      int j = s * 64 + lane;
      bool valid = (j < TOPK) && (top_s[c * TOPK + j] > CONF);
      u64 bal = __ballot(valid);
      if (lane == s) kw = bal;
    }
    // redistribute: lane L<32 holds 32-bit keep word L
    u32 keep32 = (u32)(shfl64(kw, lane >> 1) >> ((lane & 1) * 32));
    const u32* M32 = (const u32*)maskL;
    const bool ld = lane < 32;
    u32 rbuf[8];
    #pragma unroll
    for (int d = 0; d < 8; ++d)
      rbuf[d] = ld ? M32[d * 32 + lane] : 0u;
    for (int ib = 0; ib < TOPK; ib += 8) {
      #pragma unroll
      for (int d = 0; d < 8; ++d) {
        const int i = ib + d;
        u32 wv = __builtin_amdgcn_readlane(keep32, i >> 5);  // wave-uniform
        if ((wv >> (i & 31)) & 1u) keep32 &= ~rbuf[d];       // scalar branch
        int nx = ib + 8 + d;
        rbuf[d] = (ld && nx < TOPK) ? M32[nx * 32 + lane] : 0u;
      }
    }
    // compact first <=100 kept scores (cls_out pre-zeroed)
    int base = 0;
    #pragma unroll
    for (int s = 0; s < 16; ++s) {
      u32 lo = __builtin_amdgcn_readlane(keep32, 2 * s);
      u32 hi = __builtin_amdgcn_readlane(keep32, 2 * s + 1);
      u64 w = ((u64)hi << 32) | lo;
      int pos = base + __popcll(w & ((1ull << lane) - 1ull));
      if (((w >> lane) & 1ull) && pos < 100)
        cls_out[c * 128 + pos] = top_s[c * TOPK + s * 64 + lane];
      base += __popcll(w);
    }
  }
}

// ---------------------------------------------------------------------------
// Global top-100 of 80 x (<=100 per class): bitonic sort 8192 in LDS.
// ---------------------------------------------------------------------------
__global__ __launch_bounds__(512) void k_final(
    const float* __restrict__ cls_out, float* __restrict__ out) {
  __shared__ float v[8192];
  const int t = threadIdx.x;
  for (int i = t; i < 8192; i += 512) {
    float x = 0.0f;
    if (i < 8000) x = cls_out[(i / 100) * 128 + (i % 100)];
    v[i] = x;
  }
  __syncthreads();
  for (int k = 2; k <= 8192; k <<= 1)
    for (int j = k >> 1; j > 0; j >>= 1) {
      for (int p = t; p < 4096; p += 512) {
        int i  = ((p & ~(j - 1)) << 1) | (p & (j - 1));
        int ix = i | j;
        bool up = (i & k) == 0;
        float a = v[i], b = v[ix];
        if (up ? (a < b) : (a > b)) { v[i] = b; v[ix] = a; }
      }
      __syncthreads();
    }
  if (t < 100) out[t] = v[t];
}

extern "C" void kernel_launch(void* const* d_in, const int* in_sizes, int n_in,
                              void* d_out, int out_size, void* d_ws, size_t ws_size,
                              hipStream_t stream) {
  const float* scores = (const float*)d_in[0];
  const float* boxes  = (const float*)d_in[1];
  float* out = (float*)d_out;
  char* ws = (char*)d_ws;

  u32* T16     = (u32*)(ws + OFF_T16);
  u32* prefA   = (u32*)(ws + OFF_PREFA);
  u32* tgtA    = (u32*)(ws + OFF_TGTA);
  u32* cnt     = (u32*)(ws + OFF_CNT);
  float* top_s = (float*)(ws + OFF_TOPS);
  u32* top_idx = (u32*)(ws + OFF_TOPI);
  float* cls_out = (float*)(ws + OFF_CLSOUT);
  u32* ghistA  = (u32*)(ws + OFF_GHA);
  u32* ghistB  = (u32*)(ws + OFF_GHB);
  u64* cand    = (u64*)(ws + OFF_CAND);

  // zero control block (incl. cnt), hists, and cls_out, every call
  hipMemsetAsync(ws, 0, 1280, stream);
  hipMemsetAsync(ws + OFF_GHA, 0, 40960 + 81920, stream);
  hipMemsetAsync(cls_out, 0, N_CLS * 128 * sizeof(float), stream);

  k_histA<<<160, 256, 0, stream>>>(scores, ghistA);
  k_thrA<<<1, 128, 0, stream>>>(ghistA, prefA, tgtA);
  k_histB<<<160, 256, 0, stream>>>(scores, prefA, ghistB);
  k_thrB<<<1, 128, 0, stream>>>(ghistB, prefA, tgtA, T16);
  k_scatter<<<160, 256, 0, stream>>>(scores, T16, cnt, cand);
  k_sort<<<N_CLS, 256, 0, stream>>>(cand, cnt, top_s, top_idx);
  k_nms<<<N_CLS, 1024, 0, stream>>>(top_s, top_idx, boxes, cls_out);
  k_final<<<1, 512, 0, stream>>>(cls_out, out);
}

// Round 5
// 430.221 us; speedup vs baseline: 1.4729x; 1.4729x over previous
//
#include <hip/hip_runtime.h>
#include <stdint.h>

#define N_DET 20000
#define N_CLS 80
#define NELEM (N_DET * N_CLS)
#define TOPK  1000
#define CONF  0.05f
#define NMST  0.5f
#define CANDS 1280
#define SORTN 2048
#define NBLK  40   // blocks for hist/scatter passes

typedef unsigned long long u64;
typedef unsigned int u32;

__device__ inline u64 shfl64(u64 v, int src) {
  int lo = __shfl((int)(u32)v, src, 64);
  int hi = __shfl((int)(v >> 32), src, 64);
  return ((u64)(u32)hi << 32) | (u32)lo;
}

// ---------------------------------------------------------------------------
// Workspace layout (total 1,624,320 B — NO overlaps):
//   T16     @ 0        (320)
//   prefA   @ 320      (320)
//   tgtA    @ 640      (320)
//   cnt     @ 960      (320)
//   top_s   @ 1280     (320000)
//   top_idx @ 321280   (320000)
//   cls_out @ 641280   (40960)
//   ghistA  @ 682240   (40960)   [80][128] u32
//   ghistB  @ 723200   (81920)   [80][256] u32
//   cand    @ 805120   (819200)  [80][1280] u64
// ---------------------------------------------------------------------------
#define OFF_T16    0
#define OFF_PREFA  320
#define OFF_TGTA   640
#define OFF_CNT    960
#define OFF_TOPS   1280
#define OFF_TOPI   321280
#define OFF_CLSOUT 641280
#define OFF_GHA    682240
#define OFF_GHB    723200
#define OFF_CAND   805120

// ---------------------------------------------------------------------------
// Pass A: level-0 histogram, bins = float-bits >> 23 (clamped to 127).
// Coalesced float4 reads of native [N_DET][N_CLS]; 4*v % 80 never wraps.
// ---------------------------------------------------------------------------
__global__ __launch_bounds__(256) void k_histA(
    const float* __restrict__ S, u32* __restrict__ gh) {
  __shared__ u32 h[N_CLS * 129];
  for (int i = threadIdx.x; i < N_CLS * 129; i += 256) h[i] = 0;
  __syncthreads();
  const int per = NELEM / 4 / NBLK;  // 10000 float4 per block
  const float4* S4 = (const float4*)S;
  const int v0 = blockIdx.x * per;
  for (int v = v0 + threadIdx.x; v < v0 + per; v += 256) {
    float4 f = S4[v];
    int c0 = (v * 4) % N_CLS;
    u32 b0 = __float_as_uint(f.x) >> 23; if (b0 > 127u) b0 = 127u;
    u32 b1 = __float_as_uint(f.y) >> 23; if (b1 > 127u) b1 = 127u;
    u32 b2 = __float_as_uint(f.z) >> 23; if (b2 > 127u) b2 = 127u;
    u32 b3 = __float_as_uint(f.w) >> 23; if (b3 > 127u) b3 = 127u;
    atomicAdd(&h[(c0 + 0) * 129 + b0], 1u);
    atomicAdd(&h[(c0 + 1) * 129 + b1], 1u);
    atomicAdd(&h[(c0 + 2) * 129 + b2], 1u);
    atomicAdd(&h[(c0 + 3) * 129 + b3], 1u);
  }
  __syncthreads();
  for (int i = threadIdx.x; i < N_CLS * 128; i += 256) {
    u32 v = h[(i >> 7) * 129 + (i & 127)];
    if (v) atomicAdd(&gh[i], v);
  }
}

// Scan staged in LDS (padded stride 129 -> no 128-stride bank conflict).
__global__ __launch_bounds__(256) void k_thrA(
    const u32* __restrict__ gh, u32* __restrict__ prefA, u32* __restrict__ tgtA) {
  __shared__ u32 h[N_CLS * 129];
  for (int i = threadIdx.x; i < N_CLS * 128; i += 256)
    h[(i >> 7) * 129 + (i & 127)] = gh[i];
  __syncthreads();
  const int c = threadIdx.x;
  if (c >= N_CLS) return;
  u32 acc = 0;
  for (int b = 127; b >= 0; --b) {
    u32 hv = h[c * 129 + b];
    acc += hv;
    if (acc >= TOPK) { prefA[c] = (u32)b; tgtA[c] = TOPK - (acc - hv); return; }
  }
  prefA[c] = 0; tgtA[c] = TOPK;
}

// ---------------------------------------------------------------------------
// Pass B: level-1 histogram over bits [22:15] for elements in the level-0 bin.
// ---------------------------------------------------------------------------
__global__ __launch_bounds__(256) void k_histB(
    const float* __restrict__ S, const u32* __restrict__ prefA,
    u32* __restrict__ gh) {
  __shared__ u32 h[N_CLS * 257];
  __shared__ u32 pA[N_CLS];
  for (int i = threadIdx.x; i < N_CLS * 257; i += 256) h[i] = 0;
  for (int i = threadIdx.x; i < N_CLS; i += 256) pA[i] = prefA[i];
  __syncthreads();
  const int per = NELEM / 4 / NBLK;
  const float4* S4 = (const float4*)S;
  const int v0 = blockIdx.x * per;
  for (int v = v0 + threadIdx.x; v < v0 + per; v += 256) {
    float4 f = S4[v];
    int c0 = (v * 4) % N_CLS;
    u32 bb[4] = {__float_as_uint(f.x), __float_as_uint(f.y),
                 __float_as_uint(f.z), __float_as_uint(f.w)};
    #pragma unroll
    for (int k = 0; k < 4; ++k) {
      u32 e = bb[k] >> 23; if (e > 127u) e = 127u;
      if (e == pA[c0 + k])
        atomicAdd(&h[(c0 + k) * 257 + ((bb[k] >> 15) & 0xFF)], 1u);
    }
  }
  __syncthreads();
  for (int i = threadIdx.x; i < N_CLS * 256; i += 256) {
    u32 v = h[(i >> 8) * 257 + (i & 255)];
    if (v) atomicAdd(&gh[i], v);
  }
}

__global__ __launch_bounds__(256) void k_thrB(
    const u32* __restrict__ gh, const u32* __restrict__ prefA,
    const u32* __restrict__ tgtA, u32* __restrict__ T16) {
  __shared__ u32 h[N_CLS * 257];
  for (int i = threadIdx.x; i < N_CLS * 256; i += 256)
    h[(i >> 8) * 257 + (i & 255)] = gh[i];
  __syncthreads();
  const int c = threadIdx.x;
  if (c >= N_CLS) return;
  const u32 tgt = tgtA[c];
  u32 acc = 0, B1 = 0;
  for (int b = 255; b >= 0; --b) {
    acc += h[c * 257 + b];
    if (acc >= tgt) { B1 = (u32)b; break; }
  }
  T16[c] = (prefA[c] << 23) | (B1 << 15);
}

// ---------------------------------------------------------------------------
// Scatter, two-phase: LDS per-class count -> ONE global atomicAdd per
// (block,class) to reserve a range -> re-read + place at reserved offsets.
// Kills the 83k contended same-line global atomics (was 249 us).
// Per-class arrival order is block-nondeterministic; downstream sort uses the
// full (bits,~row) key (total order) so the final result is deterministic.
// ---------------------------------------------------------------------------
__global__ __launch_bounds__(256) void k_scatter(
    const float* __restrict__ S, const u32* __restrict__ T16,
    u32* __restrict__ cnt, u64* __restrict__ cand) {
  __shared__ u32 tl[N_CLS];
  __shared__ u32 lcnt[N_CLS];
  __shared__ u32 gbase[N_CLS];
  for (int i = threadIdx.x; i < N_CLS; i += 256) { tl[i] = T16[i]; lcnt[i] = 0; }
  __syncthreads();
  const int per = NELEM / 4 / NBLK;
  const float4* S4 = (const float4*)S;
  const int v0 = blockIdx.x * per;
  // pass 1: count per class within this block
  for (int v = v0 + threadIdx.x; v < v0 + per; v += 256) {
    float4 f = S4[v];
    const int c0 = (v * 4) % N_CLS;
    u32 bb[4] = {__float_as_uint(f.x), __float_as_uint(f.y),
                 __float_as_uint(f.z), __float_as_uint(f.w)};
    #pragma unroll
    for (int k = 0; k < 4; ++k)
      if (bb[k] >= tl[c0 + k]) atomicAdd(&lcnt[c0 + k], 1u);
  }
  __syncthreads();
  // reserve global ranges (one atomic per class per block)
  for (int i = threadIdx.x; i < N_CLS; i += 256) {
    u32 n = lcnt[i];
    gbase[i] = n ? atomicAdd(&cnt[i], n) : 0u;
    lcnt[i] = 0;
  }
  __syncthreads();
  // pass 2: place (scores re-read; L2/L3-hot)
  for (int v = v0 + threadIdx.x; v < v0 + per; v += 256) {
    float4 f = S4[v];
    const int base = v * 4;
    const int c0 = base % N_CLS;
    const u32 row = (u32)(base / N_CLS);
    u32 bb[4] = {__float_as_uint(f.x), __float_as_uint(f.y),
                 __float_as_uint(f.z), __float_as_uint(f.w)};
    #pragma unroll
    for (int k = 0; k < 4; ++k) {
      if (bb[k] >= tl[c0 + k]) {
        u32 p = gbase[c0 + k] + atomicAdd(&lcnt[c0 + k], 1u);
        if (p < CANDS)
          cand[(size_t)(c0 + k) * CANDS + p] = ((u64)bb[k] << 32) | (u32)(~row);
      }
    }
  }
}

// ---------------------------------------------------------------------------
// Per-class bitonic sort of candidates -> top-1000 scores + box indices.
// Key (bits<<32)|~row gives score-desc, index-asc (jax top_k tie-break).
// ---------------------------------------------------------------------------
__global__ __launch_bounds__(256) void k_sort(
    const u64* __restrict__ cand, const u32* __restrict__ cnt,
    float* __restrict__ top_s, u32* __restrict__ top_idx) {
  const int c = blockIdx.x, t = threadIdx.x;
  __shared__ u64 keys[SORTN];
  u32 n = cnt[c]; if (n > CANDS) n = CANDS;
  for (int i = t; i < SORTN; i += 256)
    keys[i] = (i < (int)n) ? cand[(size_t)c * CANDS + i] : 0ull;
  __syncthreads();
  for (int k = 2; k <= SORTN; k <<= 1)
    for (int j = k >> 1; j > 0; j >>= 1) {
      for (int p = t; p < SORTN / 2; p += 256) {
        int i  = ((p & ~(j - 1)) << 1) | (p & (j - 1));
        int ix = i | j;
        bool up = (i & k) == 0;
        u64 a = keys[i], b = keys[ix];
        if (up ? (a < b) : (a > b)) { keys[i] = b; keys[ix] = a; }
      }
      __syncthreads();
    }
  for (int i = t; i < TOPK; i += 256) {
    u64 kk = keys[i];
    u32 idx = ~(u32)kk;
    if (kk == 0ull || idx >= N_DET) idx = 0;  // pathological pad only
    top_s[c * TOPK + i] = __uint_as_float((u32)(kk >> 32));
    top_idx[c * TOPK + i] = idx;
  }
}

// ---------------------------------------------------------------------------
// NMS: mask phase (16 waves, all pairs -> 1000x1000 bitmask in LDS), then
// serial greedy sweep on wave 0 (v_readlane, ~20 cy/step chain), then
// compact top-100 kept scores. IoU uses IEEE div to bit-match numpy.
// ---------------------------------------------------------------------------
__global__ __launch_bounds__(1024) void k_nms(
    const float* __restrict__ top_s, const u32* __restrict__ top_idx,
    const float* __restrict__ boxes, float* __restrict__ cls_out) {
  const int c = blockIdx.x;
  const int tid = threadIdx.x, wave = tid >> 6, lane = tid & 63;
  __shared__ float4 sbox[TOPK];     // 16000 B
  __shared__ float sarea[TOPK];     //  4000 B
  __shared__ u64 maskL[TOPK * 16];  // 128000 B

  for (int i = tid; i < TOPK; i += 1024) {
    u32 idx = top_idx[c * TOPK + i];
    if (idx >= N_DET) idx = 0;
    float4 b = ((const float4*)boxes)[idx];
    sbox[i] = b;
    sarea[i] = (b.z - b.x) * (b.w - b.y);
  }
  __syncthreads();

  float4 cb[16]; float ca[16];
  #pragma unroll
  for (int s = 0; s < 16; ++s) {
    int j = s * 64 + lane;
    cb[s] = (j < TOPK) ? sbox[j] : make_float4(0.f, 0.f, 0.f, 0.f);
    ca[s] = (j < TOPK) ? sarea[j] : 0.f;
  }

  for (int i = wave; i < TOPK; i += 16) {
    float4 bi = sbox[i];
    float ai = sarea[i];
    const int s0 = i >> 6;
    u64 w = 0;
    #pragma unroll
    for (int s = 0; s < 16; ++s) {
      if (s >= s0) {
        int j = s * 64 + lane;
        bool sup = false;
        if (j < TOPK && j > i) {
          #pragma clang fp contract(off)
          float iw = fmaxf(fminf(bi.z, cb[s].z) - fmaxf(bi.x, cb[s].x), 0.0f);
          float ih = fmaxf(fminf(bi.w, cb[s].w) - fmaxf(bi.y, cb[s].y), 0.0f);
          float inter = iw * ih;
          float iou = inter / (ai + ca[s] - inter + 1e-9f);
          sup = iou > NMST;
        }
        u64 bal = __ballot(sup);
        if (lane == s) w = bal;
      }
    }
    if (lane < 16) maskL[i * 16 + lane] = w;
  }
  __syncthreads();

  if (wave == 0) {
    u64 kw = 0;
    for (int s = 0; s < 16; ++s) {
      int j = s * 64 + lane;
      bool valid = (j < TOPK) && (top_s[c * TOPK + j] > CONF);
      u64 bal = __ballot(valid);
      if (lane == s) kw = bal;
    }
    u32 keep32 = (u32)(shfl64(kw, lane >> 1) >> ((lane & 1) * 32));
    const u32* M32 = (const u32*)maskL;
    const bool ld = lane < 32;
    u32 rbuf[8];
    #pragma unroll
    for (int d = 0; d < 8; ++d)
      rbuf[d] = ld ? M32[d * 32 + lane] : 0u;
    for (int ib = 0; ib < TOPK; ib += 8) {
      #pragma unroll
      for (int d = 0; d < 8; ++d) {
        const int i = ib + d;
        u32 wv = __builtin_amdgcn_readlane(keep32, i >> 5);
        if ((wv >> (i & 31)) & 1u) keep32 &= ~rbuf[d];
        int nx = ib + 8 + d;
        rbuf[d] = (ld && nx < TOPK) ? M32[nx * 32 + lane] : 0u;
      }
    }
    int base = 0;
    #pragma unroll
    for (int s = 0; s < 16; ++s) {
      u32 lo = __builtin_amdgcn_readlane(keep32, 2 * s);
      u32 hi = __builtin_amdgcn_readlane(keep32, 2 * s + 1);
      u64 w = ((u64)hi << 32) | lo;
      int pos = base + __popcll(w & ((1ull << lane) - 1ull));
      if (((w >> lane) & 1ull) && pos < 100)
        cls_out[c * 128 + pos] = top_s[c * TOPK + s * 64 + lane];
      base += __popcll(w);
    }
  }
}

// ---------------------------------------------------------------------------
// Global top-100 of 80 x (<=100 per class): bitonic sort 8192 in LDS.
// ---------------------------------------------------------------------------
__global__ __launch_bounds__(512) void k_final(
    const float* __restrict__ cls_out, float* __restrict__ out) {
  __shared__ float v[8192];
  const int t = threadIdx.x;
  for (int i = t; i < 8192; i += 512) {
    float x = 0.0f;
    if (i < 8000) x = cls_out[(i / 100) * 128 + (i % 100)];
    v[i] = x;
  }
  __syncthreads();
  for (int k = 2; k <= 8192; k <<= 1)
    for (int j = k >> 1; j > 0; j >>= 1) {
      for (int p = t; p < 4096; p += 512) {
        int i  = ((p & ~(j - 1)) << 1) | (p & (j - 1));
        int ix = i | j;
        bool up = (i & k) == 0;
        float a = v[i], b = v[ix];
        if (up ? (a < b) : (a > b)) { v[i] = b; v[ix] = a; }
      }
      __syncthreads();
    }
  if (t < 100) out[t] = v[t];
}

extern "C" void kernel_launch(void* const* d_in, const int* in_sizes, int n_in,
                              void* d_out, int out_size, void* d_ws, size_t ws_size,
                              hipStream_t stream) {
  const float* scores = (const float*)d_in[0];
  const float* boxes  = (const float*)d_in[1];
  float* out = (float*)d_out;
  char* ws = (char*)d_ws;

  u32* T16     = (u32*)(ws + OFF_T16);
  u32* prefA   = (u32*)(ws + OFF_PREFA);
  u32* tgtA    = (u32*)(ws + OFF_TGTA);
  u32* cnt     = (u32*)(ws + OFF_CNT);
  float* top_s = (float*)(ws + OFF_TOPS);
  u32* top_idx = (u32*)(ws + OFF_TOPI);
  float* cls_out = (float*)(ws + OFF_CLSOUT);
  u32* ghistA  = (u32*)(ws + OFF_GHA);
  u32* ghistB  = (u32*)(ws + OFF_GHB);
  u64* cand    = (u64*)(ws + OFF_CAND);

  hipMemsetAsync(ws, 0, 1280, stream);
  hipMemsetAsync(ws + OFF_GHA, 0, 40960 + 81920, stream);
  hipMemsetAsync(cls_out, 0, N_CLS * 128 * sizeof(float), stream);

  k_histA<<<NBLK, 256, 0, stream>>>(scores, ghistA);
  k_thrA<<<1, 256, 0, stream>>>(ghistA, prefA, tgtA);
  k_histB<<<NBLK, 256, 0, stream>>>(scores, prefA, ghistB);
  k_thrB<<<1, 256, 0, stream>>>(ghistB, prefA, tgtA, T16);
  k_scatter<<<NBLK, 256, 0, stream>>>(scores, T16, cnt, cand);
  k_sort<<<N_CLS, 256, 0, stream>>>(cand, cnt, top_s, top_idx);
  k_nms<<<N_CLS, 1024, 0, stream>>>(top_s, top_idx, boxes, cls_out);
  k_final<<<1, 512, 0, stream>>>(cls_out, out);
}

// Round 6
// 343.351 us; speedup vs baseline: 1.8456x; 1.2530x over previous
//
#include <hip/hip_runtime.h>
#include <stdint.h>

#define N_DET 20000
#define N_CLS 80
#define NELEM (N_DET * N_CLS)
#define TOPK  1000
#define CONF  0.05f
#define CANDS 1280
#define SORTN 2048
#define NBLK  40   // blocks for hist/scatter passes

typedef unsigned long long u64;
typedef unsigned int u32;

__device__ inline u64 shfl64(u64 v, int src) {
  int lo = __shfl((int)(u32)v, src, 64);
  int hi = __shfl((int)(v >> 32), src, 64);
  return ((u64)(u32)hi << 32) | (u32)lo;
}

// Exact replication of RN(inter/denom) > 0.5 without fdiv:
// RN(a/b) > 0.5  <=>  a/b > 0.5 + 2^-25 (tie rounds-to-even to 0.5)
//               <=>  a * 2^25 > b * (2^24 + 1), both products exact in f64.
__device__ __forceinline__ bool iou_gt_half(float4 bi, float ai,
                                            float4 bj, float aj) {
  #pragma clang fp contract(off)
  float iw = fmaxf(fminf(bi.z, bj.z) - fmaxf(bi.x, bj.x), 0.0f);
  float ih = fmaxf(fminf(bi.w, bj.w) - fmaxf(bi.y, bj.y), 0.0f);
  float inter = iw * ih;
  float denom = ai + aj - inter + 1e-9f;
  return (double)inter * 33554432.0 > (double)denom * 16777217.0;
}

// ---------------------------------------------------------------------------
// Workspace layout (small part total 1,624,320 B — NO overlaps):
//   T16 @0 (320) | prefA @320 | tgtA @640 | cnt @960
//   top_s @1280 (320000) | top_idx @321280 (320000) | cls_out @641280 (40960)
//   ghistA @682240 (40960) | ghistB @723200 (81920) | cand @805120 (819200)
//   maskG @1624320 (10,240,000)   [only if ws_size >= 11,864,320]
// ---------------------------------------------------------------------------
#define OFF_T16    0
#define OFF_PREFA  320
#define OFF_TGTA   640
#define OFF_CNT    960
#define OFF_TOPS   1280
#define OFF_TOPI   321280
#define OFF_CLSOUT 641280
#define OFF_GHA    682240
#define OFF_GHB    723200
#define OFF_CAND   805120
#define OFF_MASK   1624320
#define MASK_BYTES (80ull * TOPK * 16 * 8)

// ---------------------------------------------------------------------------
// Pass A: level-0 histogram, bins = float-bits >> 23 (clamped to 127).
// ---------------------------------------------------------------------------
__global__ __launch_bounds__(256) void k_histA(
    const float* __restrict__ S, u32* __restrict__ gh) {
  __shared__ u32 h[N_CLS * 129];
  for (int i = threadIdx.x; i < N_CLS * 129; i += 256) h[i] = 0;
  __syncthreads();
  const int per = NELEM / 4 / NBLK;
  const float4* S4 = (const float4*)S;
  const int v0 = blockIdx.x * per;
  for (int v = v0 + threadIdx.x; v < v0 + per; v += 256) {
    float4 f = S4[v];
    int c0 = (v * 4) % N_CLS;
    u32 b0 = __float_as_uint(f.x) >> 23; if (b0 > 127u) b0 = 127u;
    u32 b1 = __float_as_uint(f.y) >> 23; if (b1 > 127u) b1 = 127u;
    u32 b2 = __float_as_uint(f.z) >> 23; if (b2 > 127u) b2 = 127u;
    u32 b3 = __float_as_uint(f.w) >> 23; if (b3 > 127u) b3 = 127u;
    atomicAdd(&h[(c0 + 0) * 129 + b0], 1u);
    atomicAdd(&h[(c0 + 1) * 129 + b1], 1u);
    atomicAdd(&h[(c0 + 2) * 129 + b2], 1u);
    atomicAdd(&h[(c0 + 3) * 129 + b3], 1u);
  }
  __syncthreads();
  for (int i = threadIdx.x; i < N_CLS * 128; i += 256) {
    u32 v = h[(i >> 7) * 129 + (i & 127)];
    if (v) atomicAdd(&gh[i], v);
  }
}

__global__ __launch_bounds__(256) void k_thrA(
    const u32* __restrict__ gh, u32* __restrict__ prefA, u32* __restrict__ tgtA) {
  __shared__ u32 h[N_CLS * 129];
  for (int i = threadIdx.x; i < N_CLS * 128; i += 256)
    h[(i >> 7) * 129 + (i & 127)] = gh[i];
  __syncthreads();
  const int c = threadIdx.x;
  if (c >= N_CLS) return;
  u32 acc = 0;
  for (int b = 127; b >= 0; --b) {
    u32 hv = h[c * 129 + b];
    acc += hv;
    if (acc >= TOPK) { prefA[c] = (u32)b; tgtA[c] = TOPK - (acc - hv); return; }
  }
  prefA[c] = 0; tgtA[c] = TOPK;
}

// ---------------------------------------------------------------------------
// Pass B: level-1 histogram over bits [22:15] for elements in the level-0 bin.
// ---------------------------------------------------------------------------
__global__ __launch_bounds__(256) void k_histB(
    const float* __restrict__ S, const u32* __restrict__ prefA,
    u32* __restrict__ gh) {
  __shared__ u32 h[N_CLS * 257];
  __shared__ u32 pA[N_CLS];
  for (int i = threadIdx.x; i < N_CLS * 257; i += 256) h[i] = 0;
  for (int i = threadIdx.x; i < N_CLS; i += 256) pA[i] = prefA[i];
  __syncthreads();
  const int per = NELEM / 4 / NBLK;
  const float4* S4 = (const float4*)S;
  const int v0 = blockIdx.x * per;
  for (int v = v0 + threadIdx.x; v < v0 + per; v += 256) {
    float4 f = S4[v];
    int c0 = (v * 4) % N_CLS;
    u32 bb[4] = {__float_as_uint(f.x), __float_as_uint(f.y),
                 __float_as_uint(f.z), __float_as_uint(f.w)};
    #pragma unroll
    for (int k = 0; k < 4; ++k) {
      u32 e = bb[k] >> 23; if (e > 127u) e = 127u;
      if (e == pA[c0 + k])
        atomicAdd(&h[(c0 + k) * 257 + ((bb[k] >> 15) & 0xFF)], 1u);
    }
  }
  __syncthreads();
  for (int i = threadIdx.x; i < N_CLS * 256; i += 256) {
    u32 v = h[(i >> 8) * 257 + (i & 255)];
    if (v) atomicAdd(&gh[i], v);
  }
}

__global__ __launch_bounds__(256) void k_thrB(
    const u32* __restrict__ gh, const u32* __restrict__ prefA,
    const u32* __restrict__ tgtA, u32* __restrict__ T16) {
  __shared__ u32 h[N_CLS * 257];
  for (int i = threadIdx.x; i < N_CLS * 256; i += 256)
    h[(i >> 8) * 257 + (i & 255)] = gh[i];
  __syncthreads();
  const int c = threadIdx.x;
  if (c >= N_CLS) return;
  const u32 tgt = tgtA[c];
  u32 acc = 0, B1 = 0;
  for (int b = 255; b >= 0; --b) {
    acc += h[c * 257 + b];
    if (acc >= tgt) { B1 = (u32)b; break; }
  }
  T16[c] = (prefA[c] << 23) | (B1 << 15);
}

// ---------------------------------------------------------------------------
// Scatter, two-phase: LDS per-class count -> ONE global atomicAdd per
// (block,class) -> re-read + place at reserved offsets.
// ---------------------------------------------------------------------------
__global__ __launch_bounds__(256) void k_scatter(
    const float* __restrict__ S, const u32* __restrict__ T16,
    u32* __restrict__ cnt, u64* __restrict__ cand) {
  __shared__ u32 tl[N_CLS];
  __shared__ u32 lcnt[N_CLS];
  __shared__ u32 gbase[N_CLS];
  for (int i = threadIdx.x; i < N_CLS; i += 256) { tl[i] = T16[i]; lcnt[i] = 0; }
  __syncthreads();
  const int per = NELEM / 4 / NBLK;
  const float4* S4 = (const float4*)S;
  const int v0 = blockIdx.x * per;
  for (int v = v0 + threadIdx.x; v < v0 + per; v += 256) {
    float4 f = S4[v];
    const int c0 = (v * 4) % N_CLS;
    u32 bb[4] = {__float_as_uint(f.x), __float_as_uint(f.y),
                 __float_as_uint(f.z), __float_as_uint(f.w)};
    #pragma unroll
    for (int k = 0; k < 4; ++k)
      if (bb[k] >= tl[c0 + k]) atomicAdd(&lcnt[c0 + k], 1u);
  }
  __syncthreads();
  for (int i = threadIdx.x; i < N_CLS; i += 256) {
    u32 n = lcnt[i];
    gbase[i] = n ? atomicAdd(&cnt[i], n) : 0u;
    lcnt[i] = 0;
  }
  __syncthreads();
  for (int v = v0 + threadIdx.x; v < v0 + per; v += 256) {
    float4 f = S4[v];
    const int base = v * 4;
    const int c0 = base % N_CLS;
    const u32 row = (u32)(base / N_CLS);
    u32 bb[4] = {__float_as_uint(f.x), __float_as_uint(f.y),
                 __float_as_uint(f.z), __float_as_uint(f.w)};
    #pragma unroll
    for (int k = 0; k < 4; ++k) {
      if (bb[k] >= tl[c0 + k]) {
        u32 p = gbase[c0 + k] + atomicAdd(&lcnt[c0 + k], 1u);
        if (p < CANDS)
          cand[(size_t)(c0 + k) * CANDS + p] = ((u64)bb[k] << 32) | (u32)(~row);
      }
    }
  }
}

// ---------------------------------------------------------------------------
// Per-class bitonic sort -> top-1000 scores + box indices.
// ---------------------------------------------------------------------------
__global__ __launch_bounds__(256) void k_sort(
    const u64* __restrict__ cand, const u32* __restrict__ cnt,
    float* __restrict__ top_s, u32* __restrict__ top_idx) {
  const int c = blockIdx.x, t = threadIdx.x;
  __shared__ u64 keys[SORTN];
  u32 n = cnt[c]; if (n > CANDS) n = CANDS;
  for (int i = t; i < SORTN; i += 256)
    keys[i] = (i < (int)n) ? cand[(size_t)c * CANDS + i] : 0ull;
  __syncthreads();
  for (int k = 2; k <= SORTN; k <<= 1)
    for (int j = k >> 1; j > 0; j >>= 1) {
      for (int p = t; p < SORTN / 2; p += 256) {
        int i  = ((p & ~(j - 1)) << 1) | (p & (j - 1));
        int ix = i | j;
        bool up = (i & k) == 0;
        u64 a = keys[i], b = keys[ix];
        if (up ? (a < b) : (a > b)) { keys[i] = b; keys[ix] = a; }
      }
      __syncthreads();
    }
  for (int i = t; i < TOPK; i += 256) {
    u64 kk = keys[i];
    u32 idx = ~(u32)kk;
    if (kk == 0ull || idx >= N_DET) idx = 0;
    top_s[c * TOPK + i] = __uint_as_float((u32)(kk >> 32));
    top_idx[c * TOPK + i] = idx;
  }
}

// ---------------------------------------------------------------------------
// PATH P (big ws): mask kernel over the whole machine.
// Grid (80 classes, 25 row-blocks of 40 rows), 256 thr. Boxes staged in LDS,
// column boxes in registers; mask rows -> global ws.
// ---------------------------------------------------------------------------
__global__ __launch_bounds__(256) void k_mask(
    const u32* __restrict__ top_idx, const float* __restrict__ boxes,
    u64* __restrict__ maskG) {
  const int c = blockIdx.x;
  const int tid = threadIdx.x, wave = tid >> 6, lane = tid & 63;
  __shared__ float4 sbox[TOPK];
  __shared__ float sarea[TOPK];
  for (int i = tid; i < TOPK; i += 256) {
    u32 idx = top_idx[c * TOPK + i];
    if (idx >= N_DET) idx = 0;
    float4 b = ((const float4*)boxes)[idx];
    sbox[i] = b;
    sarea[i] = (b.z - b.x) * (b.w - b.y);
  }
  __syncthreads();
  float4 cb[16]; float ca[16];
  #pragma unroll
  for (int s = 0; s < 16; ++s) {
    int j = s * 64 + lane;
    cb[s] = (j < TOPK) ? sbox[j] : make_float4(0.f, 0.f, 0.f, 0.f);
    ca[s] = (j < TOPK) ? sarea[j] : 0.f;
  }
  for (int rr = 0; rr < 10; ++rr) {
    const int i = blockIdx.y * 40 + wave * 10 + rr;
    float4 bi = sbox[i];
    float ai = sarea[i];
    const int s0 = i >> 6;
    u64 w = 0;
    #pragma unroll
    for (int s = 0; s < 16; ++s) {
      if (s >= s0) {  // s0 wave-uniform -> scalar-branch skip
        int j = s * 64 + lane;
        bool sup = iou_gt_half(bi, ai, cb[s], ca[s]);  // pad cols: inter==0
        if (s == s0) sup &= (j > i);
        u64 bal = __ballot(sup);
        if (lane == s) w = bal;
      }
    }
    if (lane < 16) maskG[((size_t)c * TOPK + i) * 16 + lane] = w;
  }
}

// ---------------------------------------------------------------------------
// PATH P: serial greedy sweep, one wave per class, mask from global ws,
// 16-deep prefetch to cover L3/HBM latency. Then compact top-100 kept.
// ---------------------------------------------------------------------------
__global__ __launch_bounds__(64) void k_sweep(
    const float* __restrict__ top_s, const u64* __restrict__ maskG,
    float* __restrict__ cls_out) {
  const int c = blockIdx.x;
  const int lane = threadIdx.x;
  const u32* M32 = (const u32*)(maskG + (size_t)c * TOPK * 16);
  u64 kw = 0;
  for (int s = 0; s < 16; ++s) {
    int j = s * 64 + lane;
    bool valid = (j < TOPK) && (top_s[c * TOPK + j] > CONF);
    u64 bal = __ballot(valid);
    if (lane == s) kw = bal;
  }
  u32 keep32 = (u32)(shfl64(kw, lane >> 1) >> ((lane & 1) * 32));
  const bool ld = lane < 32;
  u32 rbuf[16];
  #pragma unroll
  for (int d = 0; d < 16; ++d)
    rbuf[d] = ld ? M32[d * 32 + lane] : 0u;
  for (int ib = 0; ib + 16 <= TOPK; ib += 16) {
    #pragma unroll
    for (int d = 0; d < 16; ++d) {
      const int i = ib + d;
      u32 wv = __builtin_amdgcn_readlane(keep32, i >> 5);
      if ((wv >> (i & 31)) & 1u) keep32 &= ~rbuf[d];
      int nx = ib + 16 + d;
      rbuf[d] = (ld && nx < TOPK) ? M32[nx * 32 + lane] : 0u;
    }
  }
  #pragma unroll
  for (int d = 0; d < 8; ++d) {  // tail rows 992..999
    const int i = 992 + d;
    u32 wv = __builtin_amdgcn_readlane(keep32, i >> 5);
    if ((wv >> (i & 31)) & 1u) keep32 &= ~rbuf[d];
  }
  int base = 0;
  #pragma unroll
  for (int s = 0; s < 16; ++s) {
    u32 lo = __builtin_amdgcn_readlane(keep32, 2 * s);
    u32 hi = __builtin_amdgcn_readlane(keep32, 2 * s + 1);
    u64 w = ((u64)hi << 32) | lo;
    int pos = base + __popcll(w & ((1ull << lane) - 1ull));
    if (((w >> lane) & 1ull) && pos < 100)
      cls_out[c * 128 + pos] = top_s[c * TOPK + s * 64 + lane];
    base += __popcll(w);
  }
}

// ---------------------------------------------------------------------------
// PATH Q (small ws): fused mask(LDS)+sweep, 16 waves, 1 block/CU.
// ---------------------------------------------------------------------------
__global__ __launch_bounds__(1024) void k_nms(
    const float* __restrict__ top_s, const u32* __restrict__ top_idx,
    const float* __restrict__ boxes, float* __restrict__ cls_out) {
  const int c = blockIdx.x;
  const int tid = threadIdx.x, wave = tid >> 6, lane = tid & 63;
  __shared__ float4 sbox[TOPK];
  __shared__ float sarea[TOPK];
  __shared__ u64 maskL[TOPK * 16];

  for (int i = tid; i < TOPK; i += 1024) {
    u32 idx = top_idx[c * TOPK + i];
    if (idx >= N_DET) idx = 0;
    float4 b = ((const float4*)boxes)[idx];
    sbox[i] = b;
    sarea[i] = (b.z - b.x) * (b.w - b.y);
  }
  __syncthreads();

  float4 cb[16]; float ca[16];
  #pragma unroll
  for (int s = 0; s < 16; ++s) {
    int j = s * 64 + lane;
    cb[s] = (j < TOPK) ? sbox[j] : make_float4(0.f, 0.f, 0.f, 0.f);
    ca[s] = (j < TOPK) ? sarea[j] : 0.f;
  }

  for (int i = wave; i < TOPK; i += 16) {
    float4 bi = sbox[i];
    float ai = sarea[i];
    const int s0 = i >> 6;
    u64 w = 0;
    #pragma unroll
    for (int s = 0; s < 16; ++s) {
      if (s >= s0) {
        int j = s * 64 + lane;
        bool sup = iou_gt_half(bi, ai, cb[s], ca[s]);
        if (s == s0) sup &= (j > i);
        u64 bal = __ballot(sup);
        if (lane == s) w = bal;
      }
    }
    if (lane < 16) maskL[i * 16 + lane] = w;
  }
  __syncthreads();

  if (wave == 0) {
    u64 kw = 0;
    for (int s = 0; s < 16; ++s) {
      int j = s * 64 + lane;
      bool valid = (j < TOPK) && (top_s[c * TOPK + j] > CONF);
      u64 bal = __ballot(valid);
      if (lane == s) kw = bal;
    }
    u32 keep32 = (u32)(shfl64(kw, lane >> 1) >> ((lane & 1) * 32));
    const u32* M32 = (const u32*)maskL;
    const bool ld = lane < 32;
    u32 rbuf[8];
    #pragma unroll
    for (int d = 0; d < 8; ++d)
      rbuf[d] = ld ? M32[d * 32 + lane] : 0u;
    for (int ib = 0; ib < TOPK; ib += 8) {
      #pragma unroll
      for (int d = 0; d < 8; ++d) {
        const int i = ib + d;
        u32 wv = __builtin_amdgcn_readlane(keep32, i >> 5);
        if ((wv >> (i & 31)) & 1u) keep32 &= ~rbuf[d];
        int nx = ib + 8 + d;
        rbuf[d] = (ld && nx < TOPK) ? M32[nx * 32 + lane] : 0u;
      }
    }
    int base = 0;
    #pragma unroll
    for (int s = 0; s < 16; ++s) {
      u32 lo = __builtin_amdgcn_readlane(keep32, 2 * s);
      u32 hi = __builtin_amdgcn_readlane(keep32, 2 * s + 1);
      u64 w = ((u64)hi << 32) | lo;
      int pos = base + __popcll(w & ((1ull << lane) - 1ull));
      if (((w >> lane) & 1ull) && pos < 100)
        cls_out[c * 128 + pos] = top_s[c * TOPK + s * 64 + lane];
      base += __popcll(w);
    }
  }
}

// ---------------------------------------------------------------------------
// Global top-100 of 80 x (<=100 per class): bitonic sort 8192 in LDS.
// ---------------------------------------------------------------------------
__global__ __launch_bounds__(512) void k_final(
    const float* __restrict__ cls_out, float* __restrict__ out) {
  __shared__ float v[8192];
  const int t = threadIdx.x;
  for (int i = t; i < 8192; i += 512) {
    float x = 0.0f;
    if (i < 8000) x = cls_out[(i / 100) * 128 + (i % 100)];
    v[i] = x;
  }
  __syncthreads();
  for (int k = 2; k <= 8192; k <<= 1)
    for (int j = k >> 1; j > 0; j >>= 1) {
      for (int p = t; p < 4096; p += 512) {
        int i  = ((p & ~(j - 1)) << 1) | (p & (j - 1));
        int ix = i | j;
        bool up = (i & k) == 0;
        float a = v[i], b = v[ix];
        if (up ? (a < b) : (a > b)) { v[i] = b; v[ix] = a; }
      }
      __syncthreads();
    }
  if (t < 100) out[t] = v[t];
}

extern "C" void kernel_launch(void* const* d_in, const int* in_sizes, int n_in,
                              void* d_out, int out_size, void* d_ws, size_t ws_size,
                              hipStream_t stream) {
  const float* scores = (const float*)d_in[0];
  const float* boxes  = (const float*)d_in[1];
  float* out = (float*)d_out;
  char* ws = (char*)d_ws;

  u32* T16     = (u32*)(ws + OFF_T16);
  u32* prefA   = (u32*)(ws + OFF_PREFA);
  u32* tgtA    = (u32*)(ws + OFF_TGTA);
  u32* cnt     = (u32*)(ws + OFF_CNT);
  float* top_s = (float*)(ws + OFF_TOPS);
  u32* top_idx = (u32*)(ws + OFF_TOPI);
  float* cls_out = (float*)(ws + OFF_CLSOUT);
  u32* ghistA  = (u32*)(ws + OFF_GHA);
  u32* ghistB  = (u32*)(ws + OFF_GHB);
  u64* cand    = (u64*)(ws + OFF_CAND);
  u64* maskG   = (u64*)(ws + OFF_MASK);

  const bool bigws = (ws_size >= (size_t)OFF_MASK + MASK_BYTES);

  hipMemsetAsync(ws, 0, 1280, stream);
  hipMemsetAsync(ws + OFF_GHA, 0, 40960 + 81920, stream);
  hipMemsetAsync(cls_out, 0, N_CLS * 128 * sizeof(float), stream);

  k_histA<<<NBLK, 256, 0, stream>>>(scores, ghistA);
  k_thrA<<<1, 256, 0, stream>>>(ghistA, prefA, tgtA);
  k_histB<<<NBLK, 256, 0, stream>>>(scores, prefA, ghistB);
  k_thrB<<<1, 256, 0, stream>>>(ghistB, prefA, tgtA, T16);
  k_scatter<<<NBLK, 256, 0, stream>>>(scores, T16, cnt, cand);
  k_sort<<<N_CLS, 256, 0, stream>>>(cand, cnt, top_s, top_idx);
  if (bigws) {
    k_mask<<<dim3(N_CLS, 25), 256, 0, stream>>>(top_idx, boxes, maskG);
    k_sweep<<<N_CLS, 64, 0, stream>>>(top_s, maskG, cls_out);
  } else {
    k_nms<<<N_CLS, 1024, 0, stream>>>(top_s, top_idx, boxes, cls_out);
  }
  k_final<<<1, 512, 0, stream>>>(cls_out, out);
}

// Round 9
// 297.387 us; speedup vs baseline: 2.1308x; 1.1546x over previous
//
#include <hip/hip_runtime.h>
#include <stdint.h>

#define N_DET 20000
#define N_CLS 80
#define NELEM (N_DET * N_CLS)
#define TOPK  1000
#define CONF  0.05f
#define CANDS 1280
#define SORTN 2048
#define NBLK  40   // blocks for hist/scatter passes

typedef unsigned long long u64;
typedef unsigned int u32;

__device__ inline u64 shfl64(u64 v, int src) {
  int lo = __shfl((int)(u32)v, src, 64);
  int hi = __shfl((int)(v >> 32), src, 64);
  return ((u64)(u32)hi << 32) | (u32)lo;
}

// Exact replication of RN(inter/denom) > 0.5 without fdiv:
// RN(a/b) > 0.5  <=>  a/b > 0.5 + 2^-25 (tie rounds-to-even to 0.5)
//               <=>  a * 2^25 > b * (2^24 + 1), both products exact in f64.
__device__ __forceinline__ bool iou_gt_half(float4 bi, float ai,
                                            float4 bj, float aj) {
  #pragma clang fp contract(off)
  float iw = fmaxf(fminf(bi.z, bj.z) - fmaxf(bi.x, bj.x), 0.0f);
  float ih = fmaxf(fminf(bi.w, bj.w) - fmaxf(bi.y, bj.y), 0.0f);
  float inter = iw * ih;
  float denom = ai + aj - inter + 1e-9f;
  return (double)inter * 33554432.0 > (double)denom * 16777217.0;
}

// ---------------------------------------------------------------------------
// Workspace layout (small part total 1,624,320 B - NO overlaps):
//   T16 @0 (320) | prefA @320 | tgtA @640 | cnt @960
//   top_s @1280 (320000) | top_idx @321280 (320000) | cls_out @641280 (40960)
//   ghistA @682240 (40960) | ghistB @723200 (81920) | cand @805120 (819200)
//   maskG @1624320 (10,240,000)   [only if ws_size >= 11,864,320]
// ---------------------------------------------------------------------------
#define OFF_T16    0
#define OFF_PREFA  320
#define OFF_TGTA   640
#define OFF_CNT    960
#define OFF_TOPS   1280
#define OFF_TOPI   321280
#define OFF_CLSOUT 641280
#define OFF_GHA    682240
#define OFF_GHB    723200
#define OFF_CAND   805120
#define OFF_MASK   1624320
#define MASK_BYTES (80ull * TOPK * 16 * 8)

// ---------------------------------------------------------------------------
// Pass A: level-0 histogram, bins = float-bits >> 23 (clamped to 127).
// ---------------------------------------------------------------------------
__global__ __launch_bounds__(256) void k_histA(
    const float* __restrict__ S, u32* __restrict__ gh) {
  __shared__ u32 h[N_CLS * 129];
  for (int i = threadIdx.x; i < N_CLS * 129; i += 256) h[i] = 0;
  __syncthreads();
  const int per = NELEM / 4 / NBLK;
  const float4* S4 = (const float4*)S;
  const int v0 = blockIdx.x * per;
  for (int v = v0 + threadIdx.x; v < v0 + per; v += 256) {
    float4 f = S4[v];
    int c0 = (v * 4) % N_CLS;
    u32 b0 = __float_as_uint(f.x) >> 23; if (b0 > 127u) b0 = 127u;
    u32 b1 = __float_as_uint(f.y) >> 23; if (b1 > 127u) b1 = 127u;
    u32 b2 = __float_as_uint(f.z) >> 23; if (b2 > 127u) b2 = 127u;
    u32 b3 = __float_as_uint(f.w) >> 23; if (b3 > 127u) b3 = 127u;
    atomicAdd(&h[(c0 + 0) * 129 + b0], 1u);
    atomicAdd(&h[(c0 + 1) * 129 + b1], 1u);
    atomicAdd(&h[(c0 + 2) * 129 + b2], 1u);
    atomicAdd(&h[(c0 + 3) * 129 + b3], 1u);
  }
  __syncthreads();
  for (int i = threadIdx.x; i < N_CLS * 128; i += 256) {
    u32 v = h[(i >> 7) * 129 + (i & 127)];
    if (v) atomicAdd(&gh[i], v);
  }
}

__global__ __launch_bounds__(256) void k_thrA(
    const u32* __restrict__ gh, u32* __restrict__ prefA, u32* __restrict__ tgtA) {
  __shared__ u32 h[N_CLS * 129];
  for (int i = threadIdx.x; i < N_CLS * 128; i += 256)
    h[(i >> 7) * 129 + (i & 127)] = gh[i];
  __syncthreads();
  const int c = threadIdx.x;
  if (c >= N_CLS) return;
  u32 acc = 0;
  for (int b = 127; b >= 0; --b) {
    u32 hv = h[c * 129 + b];
    acc += hv;
    if (acc >= TOPK) { prefA[c] = (u32)b; tgtA[c] = TOPK - (acc - hv); return; }
  }
  prefA[c] = 0; tgtA[c] = TOPK;
}

// ---------------------------------------------------------------------------
// Pass B: level-1 histogram over bits [22:15] for elements in the level-0 bin.
// ---------------------------------------------------------------------------
__global__ __launch_bounds__(256) void k_histB(
    const float* __restrict__ S, const u32* __restrict__ prefA,
    u32* __restrict__ gh) {
  __shared__ u32 h[N_CLS * 257];
  __shared__ u32 pA[N_CLS];
  for (int i = threadIdx.x; i < N_CLS * 257; i += 256) h[i] = 0;
  for (int i = threadIdx.x; i < N_CLS; i += 256) pA[i] = prefA[i];
  __syncthreads();
  const int per = NELEM / 4 / NBLK;
  const float4* S4 = (const float4*)S;
  const int v0 = blockIdx.x * per;
  for (int v = v0 + threadIdx.x; v < v0 + per; v += 256) {
    float4 f = S4[v];
    int c0 = (v * 4) % N_CLS;
    u32 bb[4] = {__float_as_uint(f.x), __float_as_uint(f.y),
                 __float_as_uint(f.z), __float_as_uint(f.w)};
    #pragma unroll
    for (int k = 0; k < 4; ++k) {
      u32 e = bb[k] >> 23; if (e > 127u) e = 127u;
      if (e == pA[c0 + k])
        atomicAdd(&h[(c0 + k) * 257 + ((bb[k] >> 15) & 0xFF)], 1u);
    }
  }
  __syncthreads();
  for (int i = threadIdx.x; i < N_CLS * 256; i += 256) {
    u32 v = h[(i >> 8) * 257 + (i & 255)];
    if (v) atomicAdd(&gh[i], v);
  }
}

__global__ __launch_bounds__(256) void k_thrB(
    const u32* __restrict__ gh, const u32* __restrict__ prefA,
    const u32* __restrict__ tgtA, u32* __restrict__ T16) {
  __shared__ u32 h[N_CLS * 257];
  for (int i = threadIdx.x; i < N_CLS * 256; i += 256)
    h[(i >> 8) * 257 + (i & 255)] = gh[i];
  __syncthreads();
  const int c = threadIdx.x;
  if (c >= N_CLS) return;
  const u32 tgt = tgtA[c];
  u32 acc = 0, B1 = 0;
  for (int b = 255; b >= 0; --b) {
    acc += h[c * 257 + b];
    if (acc >= tgt) { B1 = (u32)b; break; }
  }
  T16[c] = (prefA[c] << 23) | (B1 << 15);
}

// ---------------------------------------------------------------------------
// Scatter, two-phase: LDS per-class count -> ONE global atomicAdd per
// (block,class) -> re-read + place at reserved offsets.
// ---------------------------------------------------------------------------
__global__ __launch_bounds__(256) void k_scatter(
    const float* __restrict__ S, const u32* __restrict__ T16,
    u32* __restrict__ cnt, u64* __restrict__ cand) {
  __shared__ u32 tl[N_CLS];
  __shared__ u32 lcnt[N_CLS];
  __shared__ u32 gbase[N_CLS];
  for (int i = threadIdx.x; i < N_CLS; i += 256) { tl[i] = T16[i]; lcnt[i] = 0; }
  __syncthreads();
  const int per = NELEM / 4 / NBLK;
  const float4* S4 = (const float4*)S;
  const int v0 = blockIdx.x * per;
  for (int v = v0 + threadIdx.x; v < v0 + per; v += 256) {
    float4 f = S4[v];
    const int c0 = (v * 4) % N_CLS;
    u32 bb[4] = {__float_as_uint(f.x), __float_as_uint(f.y),
                 __float_as_uint(f.z), __float_as_uint(f.w)};
    #pragma unroll
    for (int k = 0; k < 4; ++k)
      if (bb[k] >= tl[c0 + k]) atomicAdd(&lcnt[c0 + k], 1u);
  }
  __syncthreads();
  for (int i = threadIdx.x; i < N_CLS; i += 256) {
    u32 n = lcnt[i];
    gbase[i] = n ? atomicAdd(&cnt[i], n) : 0u;
    lcnt[i] = 0;
  }
  __syncthreads();
  for (int v = v0 + threadIdx.x; v < v0 + per; v += 256) {
    float4 f = S4[v];
    const int base = v * 4;
    const int c0 = base % N_CLS;
    const u32 row = (u32)(base / N_CLS);
    u32 bb[4] = {__float_as_uint(f.x), __float_as_uint(f.y),
                 __float_as_uint(f.z), __float_as_uint(f.w)};
    #pragma unroll
    for (int k = 0; k < 4; ++k) {
      if (bb[k] >= tl[c0 + k]) {
        u32 p = gbase[c0 + k] + atomicAdd(&lcnt[c0 + k], 1u);
        if (p < CANDS)
          cand[(size_t)(c0 + k) * CANDS + p] = ((u64)bb[k] << 32) | (u32)(~row);
      }
    }
  }
}

// ---------------------------------------------------------------------------
// Per-class bitonic sort -> top-1000 scores + box indices. 512 threads.
// ---------------------------------------------------------------------------
__global__ __launch_bounds__(512) void k_sort(
    const u64* __restrict__ cand, const u32* __restrict__ cnt,
    float* __restrict__ top_s, u32* __restrict__ top_idx) {
  const int c = blockIdx.x, t = threadIdx.x;
  __shared__ u64 keys[SORTN];
  u32 n = cnt[c]; if (n > CANDS) n = CANDS;
  for (int i = t; i < SORTN; i += 512)
    keys[i] = (i < (int)n) ? cand[(size_t)c * CANDS + i] : 0ull;
  __syncthreads();
  for (int k = 2; k <= SORTN; k <<= 1)
    for (int j = k >> 1; j > 0; j >>= 1) {
      for (int p = t; p < SORTN / 2; p += 512) {
        int i  = ((p & ~(j - 1)) << 1) | (p & (j - 1));
        int ix = i | j;
        bool up = (i & k) == 0;
        u64 a = keys[i], b = keys[ix];
        if (up ? (a < b) : (a > b)) { keys[i] = b; keys[ix] = a; }
      }
      __syncthreads();
    }
  for (int i = t; i < TOPK; i += 512) {
    u64 kk = keys[i];
    u32 idx = ~(u32)kk;
    if (kk == 0ull || idx >= N_DET) idx = 0;
    top_s[c * TOPK + i] = __uint_as_float((u32)(kk >> 32));
    top_idx[c * TOPK + i] = idx;
  }
}

// ---------------------------------------------------------------------------
// PATH P (big ws): mask kernel over the whole machine.
// Grid (80 classes, 25 row-blocks of 40 rows), 256 thr.
// ---------------------------------------------------------------------------
__global__ __launch_bounds__(256) void k_mask(
    const u32* __restrict__ top_idx, const float* __restrict__ boxes,
    u64* __restrict__ maskG) {
  const int c = blockIdx.x;
  const int tid = threadIdx.x, wave = tid >> 6, lane = tid & 63;
  __shared__ float4 sbox[TOPK];
  __shared__ float sarea[TOPK];
  for (int i = tid; i < TOPK; i += 256) {
    u32 idx = top_idx[c * TOPK + i];
    if (idx >= N_DET) idx = 0;
    float4 b = ((const float4*)boxes)[idx];
    sbox[i] = b;
    sarea[i] = (b.z - b.x) * (b.w - b.y);
  }
  __syncthreads();
  float4 cb[16]; float ca[16];
  #pragma unroll
  for (int s = 0; s < 16; ++s) {
    int j = s * 64 + lane;
    cb[s] = (j < TOPK) ? sbox[j] : make_float4(0.f, 0.f, 0.f, 0.f);
    ca[s] = (j < TOPK) ? sarea[j] : 0.f;
  }
  for (int rr = 0; rr < 10; ++rr) {
    const int i = blockIdx.y * 40 + wave * 10 + rr;
    float4 bi = sbox[i];
    float ai = sarea[i];
    const int s0 = i >> 6;
    u64 w = 0;
    #pragma unroll
    for (int s = 0; s < 16; ++s) {
      if (s >= s0) {
        int j = s * 64 + lane;
        bool sup = iou_gt_half(bi, ai, cb[s], ca[s]);
        if (s == s0) sup &= (j > i);
        u64 bal = __ballot(sup);
        if (lane == s) w = bal;
      }
    }
    if (lane < 16) maskG[((size_t)c * TOPK + i) * 16 + lane] = w;
  }
}

// ---------------------------------------------------------------------------
// PATH P: serial greedy sweep, one wave per class, 16-deep prefetch.
// ---------------------------------------------------------------------------
__global__ __launch_bounds__(64) void k_sweep(
    const float* __restrict__ top_s, const u64* __restrict__ maskG,
    float* __restrict__ cls_out) {
  const int c = blockIdx.x;
  const int lane = threadIdx.x;
  const u32* M32 = (const u32*)(maskG + (size_t)c * TOPK * 16);
  u64 kw = 0;
  for (int s = 0; s < 16; ++s) {
    int j = s * 64 + lane;
    bool valid = (j < TOPK) && (top_s[c * TOPK + j] > CONF);
    u64 bal = __ballot(valid);
    if (lane == s) kw = bal;
  }
  u32 keep32 = (u32)(shfl64(kw, lane >> 1) >> ((lane & 1) * 32));
  const bool ld = lane < 32;
  u32 rbuf[16];
  #pragma unroll
  for (int d = 0; d < 16; ++d)
    rbuf[d] = ld ? M32[d * 32 + lane] : 0u;
  for (int ib = 0; ib + 16 <= TOPK; ib += 16) {
    #pragma unroll
    for (int d = 0; d < 16; ++d) {
      const int i = ib + d;
      u32 wv = __builtin_amdgcn_readlane(keep32, i >> 5);
      if ((wv >> (i & 31)) & 1u) keep32 &= ~rbuf[d];
      int nx = ib + 16 + d;
      rbuf[d] = (ld && nx < TOPK) ? M32[nx * 32 + lane] : 0u;
    }
  }
  #pragma unroll
  for (int d = 0; d < 8; ++d) {  // tail rows 992..999
    const int i = 992 + d;
    u32 wv = __builtin_amdgcn_readlane(keep32, i >> 5);
    if ((wv >> (i & 31)) & 1u) keep32 &= ~rbuf[d];
  }
  int base = 0;
  #pragma unroll
  for (int s = 0; s < 16; ++s) {
    u32 lo = __builtin_amdgcn_readlane(keep32, 2 * s);
    u32 hi = __builtin_amdgcn_readlane(keep32, 2 * s + 1);
    u64 w = ((u64)hi << 32) | lo;
    int pos = base + __popcll(w & ((1ull << lane) - 1ull));
    if (((w >> lane) & 1ull) && pos < 100)
      cls_out[c * 128 + pos] = top_s[c * TOPK + s * 64 + lane];
    base += __popcll(w);
  }
}

// ---------------------------------------------------------------------------
// PATH Q (small ws): fused mask(LDS)+sweep, 16 waves, 1 block/CU.
// ---------------------------------------------------------------------------
__global__ __launch_bounds__(1024) void k_nms(
    const float* __restrict__ top_s, const u32* __restrict__ top_idx,
    const float* __restrict__ boxes, float* __restrict__ cls_out) {
  const int c = blockIdx.x;
  const int tid = threadIdx.x, wave = tid >> 6, lane = tid & 63;
  __shared__ float4 sbox[TOPK];
  __shared__ float sarea[TOPK];
  __shared__ u64 maskL[TOPK * 16];

  for (int i = tid; i < TOPK; i += 1024) {
    u32 idx = top_idx[c * TOPK + i];
    if (idx >= N_DET) idx = 0;
    float4 b = ((const float4*)boxes)[idx];
    sbox[i] = b;
    sarea[i] = (b.z - b.x) * (b.w - b.y);
  }
  __syncthreads();

  float4 cb[16]; float ca[16];
  #pragma unroll
  for (int s = 0; s < 16; ++s) {
    int j = s * 64 + lane;
    cb[s] = (j < TOPK) ? sbox[j] : make_float4(0.f, 0.f, 0.f, 0.f);
    ca[s] = (j < TOPK) ? sarea[j] : 0.f;
  }

  for (int i = wave; i < TOPK; i += 16) {
    float4 bi = sbox[i];
    float ai = sarea[i];
    const int s0 = i >> 6;
    u64 w = 0;
    #pragma unroll
    for (int s = 0; s < 16; ++s) {
      if (s >= s0) {
        int j = s * 64 + lane;
        bool sup = iou_gt_half(bi, ai, cb[s], ca[s]);
        if (s == s0) sup &= (j > i);
        u64 bal = __ballot(sup);
        if (lane == s) w = bal;
      }
    }
    if (lane < 16) maskL[i * 16 + lane] = w;
  }
  __syncthreads();

  if (wave == 0) {
    u64 kw = 0;
    for (int s = 0; s < 16; ++s) {
      int j = s * 64 + lane;
      bool valid = (j < TOPK) && (top_s[c * TOPK + j] > CONF);
      u64 bal = __ballot(valid);
      if (lane == s) kw = bal;
    }
    u32 keep32 = (u32)(shfl64(kw, lane >> 1) >> ((lane & 1) * 32));
    const u32* M32 = (const u32*)maskL;
    const bool ld = lane < 32;
    u32 rbuf[8];
    #pragma unroll
    for (int d = 0; d < 8; ++d)
      rbuf[d] = ld ? M32[d * 32 + lane] : 0u;
    for (int ib = 0; ib < TOPK; ib += 8) {
      #pragma unroll
      for (int d = 0; d < 8; ++d) {
        const int i = ib + d;
        u32 wv = __builtin_amdgcn_readlane(keep32, i >> 5);
        if ((wv >> (i & 31)) & 1u) keep32 &= ~rbuf[d];
        int nx = ib + 8 + d;
        rbuf[d] = (ld && nx < TOPK) ? M32[nx * 32 + lane] : 0u;
      }
    }
    int base = 0;
    #pragma unroll
    for (int s = 0; s < 16; ++s) {
      u32 lo = __builtin_amdgcn_readlane(keep32, 2 * s);
      u32 hi = __builtin_amdgcn_readlane(keep32, 2 * s + 1);
      u64 w = ((u64)hi << 32) | lo;
      int pos = base + __popcll(w & ((1ull << lane) - 1ull));
      if (((w >> lane) & 1ull) && pos < 100)
        cls_out[c * 128 + pos] = top_s[c * TOPK + s * 64 + lane];
      base += __popcll(w);
    }
  }
}

// ---------------------------------------------------------------------------
// Global top-100 via histogram-select (was: full 8192 bitonic, 111 us).
// 16384-bin hist of bits>>17 -> suffix scan -> threshold bin -> compact
// ~100-130 candidates -> small bitonic -> top-100. Tie-flood (>1024 cands)
// falls back to full 8192-element bitonic for unconditional exactness.
// MUST be launched with 1024 threads (scan logic assumes exactly 1024).
// ---------------------------------------------------------------------------
__global__ __launch_bounds__(1024) void k_final(
    const float* __restrict__ cls_out, float* __restrict__ out) {
  __shared__ u32 hist[16384];   // 64 KB
  __shared__ u32 vals[8192];    // 32 KB
  __shared__ u32 sfx[1024];     //  4 KB
  __shared__ u32 cands[1024];   //  4 KB
  __shared__ u32 sThr, scnt;
  const int t = threadIdx.x;

  for (int i = t; i < 16384; i += 1024) hist[i] = 0;
  if (t == 0) { sThr = 0; scnt = 0; }
  __syncthreads();
  for (int i = t; i < 8192; i += 1024) {
    u32 b = 0;
    if (i < 8000) {
      b = __float_as_uint(cls_out[(i / 100) * 128 + (i % 100)]);
      u32 bin = b >> 17; if (bin > 16383u) bin = 16383u;
      atomicAdd(&hist[bin], 1u);
    }
    vals[i] = b;
  }
  __syncthreads();
  // group sums: thread t owns bins [16t, 16t+16)
  u32 loc[16]; u32 gs = 0;
  #pragma unroll
  for (int k = 0; k < 16; ++k) { loc[k] = hist[t * 16 + k]; gs += loc[k]; }
  sfx[t] = gs;
  __syncthreads();
  for (int off = 1; off < 1024; off <<= 1) {
    u32 v = (t + off < 1024) ? sfx[t + off] : 0u;
    __syncthreads();
    sfx[t] += v;
    __syncthreads();
  }
  {
    u32 run = (t == 1023) ? 0u : sfx[t + 1];
    if (run < 100u && run + gs >= 100u) {
      #pragma unroll
      for (int k = 15; k >= 0; --k) {
        u32 nr = run + loc[k];
        if (run < 100u && nr >= 100u) sThr = ((u32)(t * 16 + k)) << 17;
        run = nr;
      }
    }
  }
  __syncthreads();
  const u32 thr = sThr;
  for (int i = t; i < 8000; i += 1024) {
    u32 v = vals[i];
    if (v >= thr) {
      u32 p = atomicAdd(&scnt, 1u);
      if (p < 1024) cands[p] = v;
    }
  }
  __syncthreads();
  const u32 nc = scnt;
  if (nc <= 1024u) {
    const int n = (nc <= 256u) ? 256 : 1024;
    for (int i = t; i < n; i += 1024)
      if (i >= (int)nc) cands[i] = 0u;
    __syncthreads();
    for (int k = 2; k <= n; k <<= 1)
      for (int j = k >> 1; j > 0; j >>= 1) {
        if (t < n / 2) {
          int i  = ((t & ~(j - 1)) << 1) | (t & (j - 1));
          int ix = i | j;
          bool up = (i & k) == 0;
          u32 a = cands[i], b = cands[ix];
          if (up ? (a < b) : (a > b)) { cands[i] = b; cands[ix] = a; }
        }
        __syncthreads();
      }
    if (t < 100) out[t] = __uint_as_float(cands[t]);
  } else {
    // tie-flood fallback: exact full sort of all 8192
    for (int k = 2; k <= 8192; k <<= 1)
      for (int j = k >> 1; j > 0; j >>= 1) {
        for (int p = t; p < 4096; p += 1024) {
          int i  = ((p & ~(j - 1)) << 1) | (p & (j - 1));
          int ix = i | j;
          bool up = (i & k) == 0;
          u32 a = vals[i], b = vals[ix];
          if (up ? (a < b) : (a > b)) { vals[i] = b; vals[ix] = a; }
        }
        __syncthreads();
      }
    if (t < 100) out[t] = __uint_as_float(vals[t]);
  }
}

extern "C" void kernel_launch(void* const* d_in, const int* in_sizes, int n_in,
                              void* d_out, int out_size, void* d_ws, size_t ws_size,
                              hipStream_t stream) {
  const float* scores = (const float*)d_in[0];
  const float* boxes  = (const float*)d_in[1];
  float* out = (float*)d_out;
  char* ws = (char*)d_ws;

  u32* T16     = (u32*)(ws + OFF_T16);
  u32* prefA   = (u32*)(ws + OFF_PREFA);
  u32* tgtA    = (u32*)(ws + OFF_TGTA);
  u32* cnt     = (u32*)(ws + OFF_CNT);
  float* top_s = (float*)(ws + OFF_TOPS);
  u32* top_idx = (u32*)(ws + OFF_TOPI);
  float* cls_out = (float*)(ws + OFF_CLSOUT);
  u32* ghistA  = (u32*)(ws + OFF_GHA);
  u32* ghistB  = (u32*)(ws + OFF_GHB);
  u64* cand    = (u64*)(ws + OFF_CAND);
  u64* maskG   = (u64*)(ws + OFF_MASK);

  const bool bigws = (ws_size >= (size_t)OFF_MASK + MASK_BYTES);

  hipMemsetAsync(ws, 0, 1280, stream);
  hipMemsetAsync(ws + OFF_GHA, 0, 40960 + 81920, stream);
  hipMemsetAsync(cls_out, 0, N_CLS * 128 * sizeof(float), stream);

  k_histA<<<NBLK, 256, 0, stream>>>(scores, ghistA);
  k_thrA<<<1, 256, 0, stream>>>(ghistA, prefA, tgtA);
  k_histB<<<NBLK, 256, 0, stream>>>(scores, prefA, ghistB);
  k_thrB<<<1, 256, 0, stream>>>(ghistB, prefA, tgtA, T16);
  k_scatter<<<NBLK, 256, 0, stream>>>(scores, T16, cnt, cand);
  k_sort<<<N_CLS, 512, 0, stream>>>(cand, cnt, top_s, top_idx);
  if (bigws) {
    k_mask<<<dim3(N_CLS, 25), 256, 0, stream>>>(top_idx, boxes, maskG);
    k_sweep<<<N_CLS, 64, 0, stream>>>(top_s, maskG, cls_out);
  } else {
    k_nms<<<N_CLS, 1024, 0, stream>>>(top_s, top_idx, boxes, cls_out);
  }
  k_final<<<1, 1024, 0, stream>>>(cls_out, out);
}